// Round 6
// baseline (117.159 us; speedup 1.0000x reference)
//
#include <hip/hip_runtime.h>
#include <hip/hip_fp16.h>
#include <stdint.h>

// Problem constants: B=32, N=2048, L=32768, D_IN=4, D=64
#define B_ 32
#define N_ 2048
#define L_ 32768

// Single fused kernel, ZERO LDS, ZERO barriers, no workspace.
// Each WAVE redundantly folds the weight chain (W_embed@W1, bias, W2 cols):
// lane f owns feature f (8 length-64 dots + bias dot, W1 reads coalesced,
// W_embed/b_embed wave-uniform -> s_load). Folded values are packed as
// splat-{v,v} half2 in VGPRs; the per-feature main loop broadcasts them with
// v_readlane (uniform loop index -> SGPR operand of v_pk_fma).
// 4 edges/thread (2 half2 edge-pairs), 1024 blocks -> 4 waves/SIMD grid-matched.
// Node gathers go straight to L2 (batch pinned to one XCD by bid&7 swizzle).

static __device__ __forceinline__ __half2 pkrn(float a, float b) {
    return __float22half2_rn(make_float2(a, b));
}

static __device__ __forceinline__ __half2 pkmax(__half2 a, __half2 b) {
    __half2 r;
    asm("v_pk_max_f16 %0, %1, %2" : "=v"(r) : "v"(a), "v"(b));
    return r;
}

static __device__ __forceinline__ int h2i(__half2 h) {
    union { __half2 h; int i; } u; u.h = h; return u.i;
}

static __device__ __forceinline__ __half2 i2h(int i) {
    union { int i; __half2 h; } u; u.i = i; return u.h;
}

__global__ __launch_bounds__(256, 4) void fused_kernel(
    const float4* __restrict__ pred_node,  // (B*N) float4 rows
    const float* __restrict__ W_embed, const float* __restrict__ b_embed,
    const float* __restrict__ W1, const float* __restrict__ b1,
    const float* __restrict__ W2, const float* __restrict__ b2,
    const int* __restrict__ esrc, const int* __restrict__ edst,
    const float2* __restrict__ lp2,        // line_param as float2 pairs
    float4* __restrict__ out) {
    const int tid = threadIdx.x;
    const int bid = blockIdx.x;          // 0..1023
    const int x = bid & 7;               // XCD (dispatch round-robin heuristic)
    const int i = bid >> 3;              // 0..127
    const int b = x + 8 * (i >> 5);      // batch: 4 batches per XCD, pinned
    const int j = i & 31;                // chunk within batch (32 x 1024 edges)
    const int ebase = b * L_ + j * 1024 + tid;

    // ---- edge indices early: HBM latency hides under the fold ----
    int sa[4], ta[4];
#pragma unroll
    for (int p = 0; p < 4; ++p) {
        sa[p] = esrc[ebase + p * 256];
        ta[p] = edst[ebase + p * 256];
    }

    // ---- per-wave redundant fold: lane f owns feature f ----
    const int f = tid & 63;
    float at0 = 0.f, at1 = 0.f, at2 = 0.f, at3 = 0.f;   // wc1[i][f] (src)
    float ab0 = 0.f, ab1 = 0.f, ab2 = 0.f, ab3 = 0.f;   // wc2[i][f] (dst)
    float bia = 0.f;
#pragma unroll 8
    for (int k = 0; k < 64; ++k) {
        float wt = W1[k * 64 + f];           // top half, coalesced per row
        float wb = W1[(64 + k) * 64 + f];    // bottom half
        float e0 = W_embed[k];               // wave-uniform -> s_load
        float e1 = W_embed[64 + k];
        float e2 = W_embed[128 + k];
        float e3 = W_embed[192 + k];
        at0 = fmaf(e0, wt, at0);
        at1 = fmaf(e1, wt, at1);
        at2 = fmaf(e2, wt, at2);
        at3 = fmaf(e3, wt, at3);
        ab0 = fmaf(e0, wb, ab0);
        ab1 = fmaf(e1, wb, ab1);
        ab2 = fmaf(e2, wb, ab2);
        ab3 = fmaf(e3, wb, ab3);
        bia = fmaf(b_embed[k], wt + wb, bia);  // b_embed uniform -> s_load
    }
    bia += b1[f];
    float2 c23 = *reinterpret_cast<const float2*>(W2 + f * 4 + 2);

    // splat-pack folded weights into per-lane VGPRs (readlane sources)
    int pw0 = h2i(pkrn(at0, at0));
    int pw1 = h2i(pkrn(at1, at1));
    int pw2 = h2i(pkrn(at2, at2));
    int pw3 = h2i(pkrn(at3, at3));
    int pw4 = h2i(pkrn(ab0, ab0));
    int pw5 = h2i(pkrn(ab1, ab1));
    int pw6 = h2i(pkrn(ab2, ab2));
    int pw7 = h2i(pkrn(ab3, ab3));
    int pwb = h2i(pkrn(bia, bia));
    int pc2 = h2i(pkrn(c23.x, c23.x));
    int pc3 = h2i(pkrn(c23.y, c23.y));

    // ---- gather node pairs (L2-resident, one XCD per batch) ----
    const float4* pnb = pred_node + b * N_;
    __half2 px[2][8];
#pragma unroll
    for (int pr = 0; pr < 2; ++pr) {
        float4 s0 = pnb[sa[2 * pr]];
        float4 s1 = pnb[sa[2 * pr + 1]];
        float4 t0 = pnb[ta[2 * pr]];
        float4 t1 = pnb[ta[2 * pr + 1]];
        px[pr][0] = pkrn(s0.x, s1.x);
        px[pr][1] = pkrn(s0.y, s1.y);
        px[pr][2] = pkrn(s0.z, s1.z);
        px[pr][3] = pkrn(s0.w, s1.w);
        px[pr][4] = pkrn(t0.x, t1.x);
        px[pr][5] = pkrn(t0.y, t1.y);
        px[pr][6] = pkrn(t0.z, t1.z);
        px[pr][7] = pkrn(t0.w, t1.w);
    }

    const __half2 zero = i2h(0);
    __half2 acc2[2] = {zero, zero};
    __half2 acc3[2] = {zero, zero};

#pragma unroll 8
    for (int ff = 0; ff < 64; ++ff) {  // weights broadcast via v_readlane
        __half2 w0 = i2h(__builtin_amdgcn_readlane(pw0, ff));
        __half2 w1 = i2h(__builtin_amdgcn_readlane(pw1, ff));
        __half2 w2 = i2h(__builtin_amdgcn_readlane(pw2, ff));
        __half2 w3 = i2h(__builtin_amdgcn_readlane(pw3, ff));
        __half2 w4 = i2h(__builtin_amdgcn_readlane(pw4, ff));
        __half2 w5 = i2h(__builtin_amdgcn_readlane(pw5, ff));
        __half2 w6 = i2h(__builtin_amdgcn_readlane(pw6, ff));
        __half2 w7 = i2h(__builtin_amdgcn_readlane(pw7, ff));
        __half2 bs = i2h(__builtin_amdgcn_readlane(pwb, ff));
        __half2 c2 = i2h(__builtin_amdgcn_readlane(pc2, ff));
        __half2 c3 = i2h(__builtin_amdgcn_readlane(pc3, ff));
#pragma unroll
        for (int pr = 0; pr < 2; ++pr) {
            __half2 h = bs;
            h = __hfma2(px[pr][0], w0, h);
            h = __hfma2(px[pr][1], w1, h);
            h = __hfma2(px[pr][2], w2, h);
            h = __hfma2(px[pr][3], w3, h);
            h = __hfma2(px[pr][4], w4, h);
            h = __hfma2(px[pr][5], w5, h);
            h = __hfma2(px[pr][6], w6, h);
            h = __hfma2(px[pr][7], w7, h);
            h = pkmax(h, zero);  // relu, single VOP3P
            acc2[pr] = __hfma2(h, c2, acc2[pr]);
            acc3[pr] = __hfma2(h, c3, acc3[pr]);
        }
    }

    // ---- epilogue ----
    float bias2 = b2[2], bias3 = b2[3];  // uniform -> s_load
#pragma unroll
    for (int p = 0; p < 4; ++p) {
        int e = ebase + p * 256;
        float2 lp = lp2[(size_t)e * 2];  // line_param[e][0:2]
        int pr = p >> 1;
        float r2 = (p & 1) ? __high2float(acc2[pr]) : __low2float(acc2[pr]);
        float r3 = (p & 1) ? __high2float(acc3[pr]) : __low2float(acc3[pr]);
        out[e] = make_float4(lp.x, lp.y, bias2 + r2, bias3 + r3);
    }
}

extern "C" void kernel_launch(void* const* d_in, const int* in_sizes, int n_in,
                              void* d_out, int out_size, void* d_ws, size_t ws_size,
                              hipStream_t stream) {
    const float* pred_node = (const float*)d_in[0];   // (B,N,4)
    const float* line_param = (const float*)d_in[1];  // (B,L,4)
    const float* W_embed = (const float*)d_in[2];     // (4,64)
    const float* b_embed = (const float*)d_in[3];     // (64,)
    const float* W1 = (const float*)d_in[4];          // (128,64)
    const float* b1 = (const float*)d_in[5];          // (64,)
    const float* W2 = (const float*)d_in[6];          // (64,4)
    const float* b2 = (const float*)d_in[7];          // (4,)
    const int* esrc = (const int*)d_in[8];            // (B,L)
    const int* edst = (const int*)d_in[9];            // (B,L)
    float* out = (float*)d_out;                       // (B,L,4)

    fused_kernel<<<1024, 256, 0, stream>>>((const float4*)pred_node,
                                           W_embed, b_embed, W1, b1, W2, b2,
                                           esrc, edst,
                                           (const float2*)line_param,
                                           (float4*)out);
}

// Round 7
// 116.803 us; speedup vs baseline: 1.0030x; 1.0030x over previous
//
#include <hip/hip_runtime.h>
#include <hip/hip_fp16.h>
#include <stdint.h>

// Problem constants: B=32, N=2048, L=32768, D_IN=4, D=64
#define B_ 32
#define N_ 2048
#define L_ 32768

// Single fused kernel, LDS = 1.5 KB weight table ONLY (no node staging).
//   1. issue this thread's 2 edge-index pairs (HBM latency hides under fold)
//   2. block-parallel fold: thread (f = tid&63, g = tid>>6) computes
//      wc1[g][f], wc2[g][f] (two length-64 dots over W1 cols, coalesced);
//      g==0 adds merged bias; packs splat-{v,v} half2 into LDS table.
//   3. ONE barrier.
//   4. gather 2 node-pairs straight from L2 (batch pinned to one XCD by the
//      bid&7 swizzle; 32 KB table per batch is L2-resident), pack 2 edges
//      per half2 slot.
//   5. main loop, 64 features: 3x uniform-address ds_read_b128 (broadcast,
//      conflict-free) + 11 VOP3P for 2 edges.
// Table layout (12 half2 = 3 float4 per feature f):
//   [f*12+0..3]={wc1[i][f]} i=0..3 | [f*12+4..7]={wc2[i][f]} | [f*12+8]={bias}
//   [f*12+9]={W2[f][2]} | [f*12+10]={W2[f][3]} | [f*12+11]=pad

static __device__ __forceinline__ __half2 pkrn(float a, float b) {
    return __float22half2_rn(make_float2(a, b));
}

static __device__ __forceinline__ __half2 pkmax(__half2 a, __half2 b) {
    __half2 r;
    asm("v_pk_max_f16 %0, %1, %2" : "=v"(r) : "v"(a), "v"(b));
    return r;
}

static __device__ __forceinline__ __half2 bits_h2(float x) {
    union { float f; __half2 h; } u;
    u.f = x;
    return u.h;
}

__global__ __launch_bounds__(256, 8) void fused_kernel(
    const float4* __restrict__ pred_node,  // (B*N) float4 rows
    const float* __restrict__ W_embed, const float* __restrict__ b_embed,
    const float* __restrict__ W1, const float* __restrict__ b1,
    const float* __restrict__ W2, const float* __restrict__ b2,
    const int* __restrict__ esrc, const int* __restrict__ edst,
    const float2* __restrict__ lp2,        // line_param as float2 pairs
    float4* __restrict__ out) {
    __shared__ __align__(16) __half2 swh[64 * 12];  // 1.5 KB folded weights

    const int tid = threadIdx.x;
    const int bid = blockIdx.x;          // 0..2047
    const int x = bid & 7;               // XCD (dispatch round-robin heuristic)
    const int i = bid >> 3;              // 0..255
    const int b = x + 8 * (i >> 6);      // batch 0..31: 4 batches/XCD, pinned
    const int j = i & 63;                // chunk within batch (64 x 512 edges)
    const int ebase = b * L_ + j * 512 + tid;  // edge0; edge1 = ebase+256

    // ---- edge indices early: HBM latency hides under the fold ----
    int s0 = esrc[ebase], s1 = esrc[ebase + 256];
    int t0 = edst[ebase], t1 = edst[ebase + 256];

    // ---- block-parallel fold: thread (f, g) does 2 length-64 dots ----
    {
        const int f = tid & 63;   // feature column (lane -> W1 coalesced)
        const int g = tid >> 6;   // input dim (wave-uniform)
        float acc_t = 0.f, acc_b = 0.f, acc_bias = 0.f;
#pragma unroll 8
        for (int k = 0; k < 64; ++k) {
            float wt = W1[k * 64 + f];          // top half col f
            float wb = W1[(64 + k) * 64 + f];   // bottom half col f
            float we = W_embed[g * 64 + k];     // wave-uniform -> s_load
            acc_t = fmaf(we, wt, acc_t);
            acc_b = fmaf(we, wb, acc_b);
            if (g == 0) acc_bias = fmaf(b_embed[k], wt + wb, acc_bias);
        }
        swh[f * 12 + g] = pkrn(acc_t, acc_t);
        swh[f * 12 + 4 + g] = pkrn(acc_b, acc_b);
        if (g == 0) {             // wave-uniform branches
            float bv = acc_bias + b1[f];
            swh[f * 12 + 8] = pkrn(bv, bv);
        } else if (g == 1) {
            float c2 = W2[f * 4 + 2];
            swh[f * 12 + 9] = pkrn(c2, c2);
        } else if (g == 2) {
            float c3 = W2[f * 4 + 3];
            swh[f * 12 + 10] = pkrn(c3, c3);
        } else {
            swh[f * 12 + 11] = pkrn(0.f, 0.f);
        }
    }

    __syncthreads();  // weight table ready (only barrier)

    // ---- gather node pairs straight from L2; pack 2 edges per slot ----
    const float4* pnb = pred_node + b * N_;
    float4 vs0 = pnb[s0];
    float4 vs1 = pnb[s1];
    float4 vt0 = pnb[t0];
    float4 vt1 = pnb[t1];

    __half2 px0 = pkrn(vs0.x, vs1.x);
    __half2 px1 = pkrn(vs0.y, vs1.y);
    __half2 px2 = pkrn(vs0.z, vs1.z);
    __half2 px3 = pkrn(vs0.w, vs1.w);
    __half2 px4 = pkrn(vt0.x, vt1.x);
    __half2 px5 = pkrn(vt0.y, vt1.y);
    __half2 px6 = pkrn(vt0.z, vt1.z);
    __half2 px7 = pkrn(vt0.w, vt1.w);

    const __half2 zero = pkrn(0.f, 0.f);
    __half2 acc2 = zero, acc3 = zero;

#pragma unroll 4
    for (int f = 0; f < 64; ++f) {  // weights: 3x uniform ds_read_b128
        const float4* wv = reinterpret_cast<const float4*>(swh) + f * 3;
        float4 q0 = wv[0], q1 = wv[1], q2 = wv[2];
        __half2 h = bits_h2(q2.x);              // bias
        h = __hfma2(px0, bits_h2(q0.x), h);
        h = __hfma2(px1, bits_h2(q0.y), h);
        h = __hfma2(px2, bits_h2(q0.z), h);
        h = __hfma2(px3, bits_h2(q0.w), h);
        h = __hfma2(px4, bits_h2(q1.x), h);
        h = __hfma2(px5, bits_h2(q1.y), h);
        h = __hfma2(px6, bits_h2(q1.z), h);
        h = __hfma2(px7, bits_h2(q1.w), h);
        h = pkmax(h, zero);                     // relu, single VOP3P
        acc2 = __hfma2(h, bits_h2(q2.y), acc2);
        acc3 = __hfma2(h, bits_h2(q2.z), acc3);
    }

    // ---- epilogue ----
    float bias2 = b2[2], bias3 = b2[3];  // uniform -> s_load
    float2 lp0 = lp2[(size_t)ebase * 2];
    float2 lp1 = lp2[(size_t)(ebase + 256) * 2];
    out[ebase] = make_float4(lp0.x, lp0.y,
                             bias2 + __low2float(acc2),
                             bias3 + __low2float(acc3));
    out[ebase + 256] = make_float4(lp1.x, lp1.y,
                                   bias2 + __high2float(acc2),
                                   bias3 + __high2float(acc3));
}

extern "C" void kernel_launch(void* const* d_in, const int* in_sizes, int n_in,
                              void* d_out, int out_size, void* d_ws, size_t ws_size,
                              hipStream_t stream) {
    const float* pred_node = (const float*)d_in[0];   // (B,N,4)
    const float* line_param = (const float*)d_in[1];  // (B,L,4)
    const float* W_embed = (const float*)d_in[2];     // (4,64)
    const float* b_embed = (const float*)d_in[3];     // (64,)
    const float* W1 = (const float*)d_in[4];          // (128,64)
    const float* b1 = (const float*)d_in[5];          // (64,)
    const float* W2 = (const float*)d_in[6];          // (64,4)
    const float* b2 = (const float*)d_in[7];          // (4,)
    const int* esrc = (const int*)d_in[8];            // (B,L)
    const int* edst = (const int*)d_in[9];            // (B,L)
    float* out = (float*)d_out;                       // (B,L,4)

    fused_kernel<<<2048, 256, 0, stream>>>((const float4*)pred_node,
                                           W_embed, b_embed, W1, b1, W2, b2,
                                           esrc, edst,
                                           (const float2*)line_param,
                                           (float4*)out);
}